// Round 1
// baseline (2467.798 us; speedup 1.0000x reference)
//
#include <hip/hip_runtime.h>

#define SEQ 512
#define T3 1536
#define CDIM 768
#define NH 12
#define HD 64
#define NL 6

typedef __attribute__((ext_vector_type(8))) short bh8;
typedef __attribute__((ext_vector_type(4))) float f4;

__device__ inline short f2bf(float f) {
    union { float f; unsigned u; } x; x.f = f;
    unsigned r = x.u + 0x7FFFu + ((x.u >> 16) & 1u);
    return (short)(r >> 16);
}

__device__ inline bh8 cvt8(const float* p) {
    f4 a = *(const f4*)p;
    f4 b = *(const f4*)(p + 4);
    bh8 r;
    r[0] = f2bf(a[0]); r[1] = f2bf(a[1]); r[2] = f2bf(a[2]); r[3] = f2bf(a[3]);
    r[4] = f2bf(b[0]); r[5] = f2bf(b[1]); r[6] = f2bf(b[2]); r[7] = f2bf(b[3]);
    return r;
}

__device__ inline float block_sum(float v, volatile float* red, int tid) {
    #pragma unroll
    for (int off = 32; off > 0; off >>= 1) v += __shfl_down(v, off, 64);
    __syncthreads();               // protect red from previous use
    if ((tid & 63) == 0) red[tid >> 6] = v;
    __syncthreads();
    return red[0] + red[1] + red[2] + red[3];
}

// ---------------- embedding + LN0 ----------------
__global__ __launch_bounds__(256) void embed_ln0_k(
        const float* __restrict__ states, const float* __restrict__ actions,
        const float* __restrict__ goals, const int* __restrict__ timesteps,
        const float* __restrict__ W_s, const float* __restrict__ b_s,
        const float* __restrict__ W_a, const float* __restrict__ b_a,
        const float* __restrict__ W_g, const float* __restrict__ b_g,
        const float* __restrict__ E_t, const float* __restrict__ g0,
        const float* __restrict__ bb0, float* __restrict__ x) {
    int row = blockIdx.x;            // b*T3 + t3
    int b = row / T3, t3 = row - b * T3;
    int t = t3 / 3, kind = t3 - t * 3;
    __shared__ float inv[64];
    __shared__ float xr[CDIM];
    __shared__ float red[4];
    int tid = threadIdx.x;
    const float* src; const float* W; const float* bias;
    if (kind == 0)      { src = goals + b * 64;                 W = W_g; bias = b_g; }
    else if (kind == 1) { src = states + ((size_t)b * SEQ + t) * 64;  W = W_s; bias = b_s; }
    else                { src = actions + ((size_t)b * SEQ + t) * 64; W = W_a; bias = b_a; }
    if (tid < 64) inv[tid] = src[tid];
    __syncthreads();
    int ts = timesteps[b * SEQ + t];
    for (int c = tid; c < CDIM; c += 256) {
        float acc = bias[c] + E_t[(size_t)ts * CDIM + c];
        #pragma unroll 8
        for (int kk = 0; kk < 64; ++kk) acc += inv[kk] * W[kk * CDIM + c];
        xr[c] = acc;
    }
    __syncthreads();
    float v0 = xr[tid], v1 = xr[tid + 256], v2 = xr[tid + 512];
    float mean = block_sum(v0 + v1 + v2, red, tid) * (1.f / CDIM);
    float d0 = v0 - mean, d1 = v1 - mean, d2 = v2 - mean;
    float var = block_sum(d0 * d0 + d1 * d1 + d2 * d2, red, tid) * (1.f / CDIM);
    float rs = rsqrtf(var + 1e-5f);
    float* w = x + (size_t)row * CDIM;
    w[tid]       = d0 * rs * g0[tid]       + bb0[tid];
    w[tid + 256] = d1 * rs * g0[tid + 256] + bb0[tid + 256];
    w[tid + 512] = d2 * rs * g0[tid + 512] + bb0[tid + 512];
}

// ---------------- LayerNorm ----------------
__global__ __launch_bounds__(256) void ln_k(const float* __restrict__ in, float* __restrict__ outp,
                                            const float* __restrict__ g, const float* __restrict__ bb) {
    int row = blockIdx.x, tid = threadIdx.x;
    __shared__ float red[4];
    const float* r = in + (size_t)row * CDIM;
    float v0 = r[tid], v1 = r[tid + 256], v2 = r[tid + 512];
    float mean = block_sum(v0 + v1 + v2, red, tid) * (1.f / CDIM);
    float d0 = v0 - mean, d1 = v1 - mean, d2 = v2 - mean;
    float var = block_sum(d0 * d0 + d1 * d1 + d2 * d2, red, tid) * (1.f / CDIM);
    float rs = rsqrtf(var + 1e-5f);
    float* w = outp + (size_t)row * CDIM;
    w[tid]       = d0 * rs * g[tid]       + bb[tid];
    w[tid + 256] = d1 * rs * g[tid + 256] + bb[tid + 256];
    w[tid + 512] = d2 * rs * g[tid + 512] + bb[tid + 512];
}

// ---------------- generic 64x64 MFMA GEMM ----------------
// EPI 0: QKV -> bf16 scatter to [B,H,T3,D] (z selects q/k/v)
// EPI 1: out = acc + bias + res   (f32)
// EPI 2: out = gelu(acc + bias)   (f32)
template<int EPI>
__global__ __launch_bounds__(256) void gemm_k(
        const float* __restrict__ A, const float* __restrict__ B0,
        const float* __restrict__ B1, const float* __restrict__ B2,
        const float* __restrict__ bias0, const float* __restrict__ bias1,
        const float* __restrict__ bias2, const float* __restrict__ res,
        float* __restrict__ outF, short* __restrict__ outQ,
        short* __restrict__ outK, short* __restrict__ outV,
        int M, int N, int K) {
    const float* Bw = B0; const float* bias = bias0; short* outB = outQ;
    if (EPI == 0) {
        if (blockIdx.z == 1) { Bw = B1; bias = bias1; outB = outK; }
        else if (blockIdx.z == 2) { Bw = B2; bias = bias2; outB = outV; }
    }
    __shared__ short As[64][40];   // [m][k] bf16, padded
    __shared__ short Bs[64][40];   // [n][k] bf16 (B^T), padded
    int tid = threadIdx.x;
    int lane = tid & 63, wave = tid >> 6;
    int wm = wave >> 1, wn = wave & 1;
    int lr = lane & 15, lg = lane >> 4;
    int bm = blockIdx.y * 64, bn = blockIdx.x * 64;
    f4 acc[2][2] = {};
    int ar = tid >> 2, ac = (tid & 3) * 8;
    int bk = tid >> 3, bn0 = (tid & 7) * 8;
    for (int k0 = 0; k0 < K; k0 += 32) {
        // stage A tile 64x32
        *(bh8*)&As[ar][ac] = cvt8(A + (size_t)(bm + ar) * K + k0 + ac);
        // stage B tile 32x64 transposed
        {
            const float* bs = Bw + (size_t)(k0 + bk) * N + bn + bn0;
            f4 f0 = *(const f4*)bs; f4 f1 = *(const f4*)(bs + 4);
            Bs[bn0 + 0][bk] = f2bf(f0[0]); Bs[bn0 + 1][bk] = f2bf(f0[1]);
            Bs[bn0 + 2][bk] = f2bf(f0[2]); Bs[bn0 + 3][bk] = f2bf(f0[3]);
            Bs[bn0 + 4][bk] = f2bf(f1[0]); Bs[bn0 + 5][bk] = f2bf(f1[1]);
            Bs[bn0 + 6][bk] = f2bf(f1[2]); Bs[bn0 + 7][bk] = f2bf(f1[3]);
        }
        __syncthreads();
        #pragma unroll
        for (int mi = 0; mi < 2; ++mi) {
            bh8 af = *(const bh8*)&As[wm * 32 + mi * 16 + lr][lg * 8];
            #pragma unroll
            for (int ni = 0; ni < 2; ++ni) {
                bh8 bf = *(const bh8*)&Bs[wn * 32 + ni * 16 + lr][lg * 8];
                acc[mi][ni] = __builtin_amdgcn_mfma_f32_16x16x32_bf16(af, bf, acc[mi][ni], 0, 0, 0);
            }
        }
        __syncthreads();
    }
    #pragma unroll
    for (int mi = 0; mi < 2; ++mi)
    #pragma unroll
    for (int ni = 0; ni < 2; ++ni)
    #pragma unroll
    for (int i = 0; i < 4; ++i) {
        int row = bm + wm * 32 + mi * 16 + lg * 4 + i;
        int col = bn + wn * 32 + ni * 16 + lr;
        float vacc = acc[mi][ni][i] + bias[col];
        if (EPI == 0) {
            int b = row / T3, t = row - b * T3;
            int h = col >> 6, d = col & 63;
            outB[((((size_t)b * NH + h) * T3 + t) << 6) + d] = f2bf(vacc);
        } else if (EPI == 1) {
            outF[(size_t)row * N + col] = vacc + res[(size_t)row * N + col];
        } else {
            outF[(size_t)row * N + col] = 0.5f * vacc * (1.0f + erff(vacc * 0.70710678118f));
        }
    }
}

// ---------------- causal flash attention ----------------
__global__ __launch_bounds__(256) void attn_k(const short* __restrict__ q, const short* __restrict__ k,
                                              const short* __restrict__ v, float* __restrict__ att) {
    int qt = blockIdx.x;     // q tile of 64 rows
    int bh = blockIdx.y;     // b*NH + h
    int b = bh / NH, h = bh - b * NH;
    const short* qb = q + (size_t)bh * T3 * HD;
    const short* kb = k + (size_t)bh * T3 * HD;
    const short* vb = v + (size_t)bh * T3 * HD;
    __shared__ short Kt[64][72];       // [token][d]
    __shared__ short Vt[64][72];       // [d][token]
    __shared__ short Pl[4][16][72];    // per-wave P
    int tid = threadIdx.x, lane = tid & 63, wave = tid >> 6;
    int lr = lane & 15, lg = lane >> 4;
    int qrow0 = qt * 64 + wave * 16;
    bh8 aq0 = *(const bh8*)(qb + (size_t)(qrow0 + lr) * HD + lg * 8);
    bh8 aq1 = *(const bh8*)(qb + (size_t)(qrow0 + lr) * HD + 32 + lg * 8);
    f4 o[4] = {};
    float mrow[4], lrow[4];
    #pragma unroll
    for (int i = 0; i < 4; ++i) { mrow[i] = -1e30f; lrow[i] = 0.f; }
    int stok = tid >> 2, sd0 = (tid & 3) * 16;
    for (int kt = 0; kt <= qt; ++kt) {
        const short* ks = kb + (size_t)(kt * 64 + stok) * HD + sd0;
        bh8 kv0 = *(const bh8*)ks, kv1 = *(const bh8*)(ks + 8);
        *(bh8*)&Kt[stok][sd0]     = kv0;
        *(bh8*)&Kt[stok][sd0 + 8] = kv1;
        const short* vs = vb + (size_t)(kt * 64 + stok) * HD + sd0;
        bh8 vv0 = *(const bh8*)vs, vv1 = *(const bh8*)(vs + 8);
        #pragma unroll
        for (int i = 0; i < 8; ++i) { Vt[sd0 + i][stok] = vv0[i]; Vt[sd0 + 8 + i][stok] = vv1[i]; }
        __syncthreads();
        f4 s[4];
        #pragma unroll
        for (int nf = 0; nf < 4; ++nf) {
            bh8 bk0 = *(const bh8*)&Kt[nf * 16 + lr][lg * 8];
            bh8 bk1 = *(const bh8*)&Kt[nf * 16 + lr][32 + lg * 8];
            f4 t = {};
            t = __builtin_amdgcn_mfma_f32_16x16x32_bf16(aq0, bk0, t, 0, 0, 0);
            t = __builtin_amdgcn_mfma_f32_16x16x32_bf16(aq1, bk1, t, 0, 0, 0);
            #pragma unroll
            for (int i = 0; i < 4; ++i) s[nf][i] = t[i] * 0.125f;
        }
        if (kt == qt) {
            #pragma unroll
            for (int nf = 0; nf < 4; ++nf)
            #pragma unroll
            for (int i = 0; i < 4; ++i) {
                int qr = wave * 16 + lg * 4 + i;
                int tc = nf * 16 + lr;
                if (tc > qr) s[nf][i] = -1e30f;
            }
        }
        #pragma unroll
        for (int i = 0; i < 4; ++i) {
            float mt = fmaxf(fmaxf(s[0][i], s[1][i]), fmaxf(s[2][i], s[3][i]));
            #pragma unroll
            for (int off = 8; off > 0; off >>= 1) mt = fmaxf(mt, __shfl_xor(mt, off, 16));
            float mn = fmaxf(mrow[i], mt);
            float fs = expf(mrow[i] - mn);
            float ps = 0.f;
            #pragma unroll
            for (int nf = 0; nf < 4; ++nf) { float p = expf(s[nf][i] - mn); s[nf][i] = p; ps += p; }
            #pragma unroll
            for (int off = 8; off > 0; off >>= 1) ps += __shfl_xor(ps, off, 16);
            mrow[i] = mn;
            lrow[i] = lrow[i] * fs + ps;
            #pragma unroll
            for (int nf = 0; nf < 4; ++nf) o[nf][i] *= fs;
            #pragma unroll
            for (int nf = 0; nf < 4; ++nf) Pl[wave][lg * 4 + i][nf * 16 + lr] = f2bf(s[nf][i]);
        }
        #pragma unroll
        for (int nf = 0; nf < 4; ++nf) {
            #pragma unroll
            for (int kk = 0; kk < 2; ++kk) {
                bh8 ap = *(const bh8*)&Pl[wave][lr][kk * 32 + lg * 8];
                bh8 bv = *(const bh8*)&Vt[nf * 16 + lr][kk * 32 + lg * 8];
                o[nf] = __builtin_amdgcn_mfma_f32_16x16x32_bf16(ap, bv, o[nf], 0, 0, 0);
            }
        }
        __syncthreads();
    }
    #pragma unroll
    for (int nf = 0; nf < 4; ++nf)
    #pragma unroll
    for (int i = 0; i < 4; ++i) {
        int qrow = qrow0 + lg * 4 + i;
        int d = nf * 16 + lr;
        att[((size_t)b * T3 + qrow) * CDIM + h * 64 + d] = o[nf][i] / lrow[i];
    }
}

// ---------------- output heads ----------------
__global__ __launch_bounds__(64) void head_k(const float* __restrict__ x,
                                             const float* __restrict__ Wps, const float* __restrict__ bps,
                                             const float* __restrict__ Wpa, const float* __restrict__ bpa,
                                             float* __restrict__ out) {
    int o = blockIdx.y;               // 0: state_preds (kind 2), 1: action_preds (kind 1)
    int bs = blockIdx.x;
    int b = bs >> 9, t = bs & 511;
    int kind = (o == 0) ? 2 : 1;
    const float* W = (o == 0) ? Wps : Wpa;
    const float* bi = (o == 0) ? bps : bpa;
    const float* xr = x + ((size_t)b * T3 + t * 3 + kind) * CDIM;
    int n = threadIdx.x;
    float a0 = 0.f, a1 = 0.f, a2 = 0.f, a3 = 0.f;
    for (int kk = 0; kk < CDIM; kk += 4) {
        a0 = fmaf(xr[kk],     W[(kk)     * 64 + n], a0);
        a1 = fmaf(xr[kk + 1], W[(kk + 1) * 64 + n], a1);
        a2 = fmaf(xr[kk + 2], W[(kk + 2) * 64 + n], a2);
        a3 = fmaf(xr[kk + 3], W[(kk + 3) * 64 + n], a3);
    }
    float acc = bi[n] + ((a0 + a1) + (a2 + a3));
    if (o == 1) acc = tanhf(acc);
    out[(((size_t)o * 2 + b) * SEQ + t) * 64 + n] = acc;
}

extern "C" void kernel_launch(void* const* d_in, const int* in_sizes, int n_in,
                              void* d_out, int out_size, void* d_ws, size_t ws_size,
                              hipStream_t stream) {
    const float* states   = (const float*)d_in[0];
    const float* actions  = (const float*)d_in[1];
    const float* goals    = (const float*)d_in[2];
    const int*   timesteps= (const int*)d_in[4];
    const float* W_s = (const float*)d_in[5];  const float* b_s = (const float*)d_in[6];
    const float* W_a = (const float*)d_in[7];  const float* b_a = (const float*)d_in[8];
    const float* W_g = (const float*)d_in[9];  const float* b_g = (const float*)d_in[10];
    const float* E_t = (const float*)d_in[11];
    const float* ln0_g = (const float*)d_in[12]; const float* ln0_b = (const float*)d_in[13];
    const float* Wq = (const float*)d_in[14]; const float* bq = (const float*)d_in[15];
    const float* Wk = (const float*)d_in[16]; const float* bk = (const float*)d_in[17];
    const float* Wv = (const float*)d_in[18]; const float* bv = (const float*)d_in[19];
    const float* Wp = (const float*)d_in[20]; const float* bp = (const float*)d_in[21];
    const float* ln1_g = (const float*)d_in[22]; const float* ln1_b = (const float*)d_in[23];
    const float* W1 = (const float*)d_in[24]; const float* b1 = (const float*)d_in[25];
    const float* W2 = (const float*)d_in[26]; const float* b2 = (const float*)d_in[27];
    const float* ln2_g = (const float*)d_in[28]; const float* ln2_b = (const float*)d_in[29];
    const float* W_ps = (const float*)d_in[30]; const float* b_ps = (const float*)d_in[31];
    const float* W_pa = (const float*)d_in[32]; const float* b_pa = (const float*)d_in[33];

    char* ws = (char*)d_ws;
    float* x    = (float*)(ws);                    //  9.44 MB  [3072,768]
    float* x2   = (float*)(ws + 9437184);          //  9.44 MB
    float* att  = (float*)(ws + 18874368);         //  9.44 MB
    float* hbuf = (float*)(ws + 28311552);         // 37.75 MB  [3072,3072]
    short* qb   = (short*)(ws + 66060288);         //  4.72 MB bf16 [B,H,T3,D]
    short* kb   = (short*)(ws + 70778880);
    short* vb   = (short*)(ws + 75497472);

    embed_ln0_k<<<dim3(2 * T3), 256, 0, stream>>>(states, actions, goals, timesteps,
        W_s, b_s, W_a, b_a, W_g, b_g, E_t, ln0_g, ln0_b, x);

    for (int l = 0; l < NL; ++l) {
        size_t wo = (size_t)l * CDIM * CDIM, bo = (size_t)l * CDIM;
        size_t w1o = (size_t)l * CDIM * 4 * CDIM, b1o = (size_t)l * 4 * CDIM;
        gemm_k<0><<<dim3(12, 48, 3), 256, 0, stream>>>(x, Wq + wo, Wk + wo, Wv + wo,
            bq + bo, bk + bo, bv + bo, nullptr, nullptr, qb, kb, vb, 3072, CDIM, CDIM);
        attn_k<<<dim3(24, 24), 256, 0, stream>>>(qb, kb, vb, att);
        gemm_k<1><<<dim3(12, 48, 1), 256, 0, stream>>>(att, Wp + wo, nullptr, nullptr,
            bp + bo, nullptr, nullptr, x, x2, nullptr, nullptr, nullptr, 3072, CDIM, CDIM);
        ln_k<<<dim3(2 * T3), 256, 0, stream>>>(x2, x, ln1_g + bo, ln1_b + bo);
        gemm_k<2><<<dim3(48, 48, 1), 256, 0, stream>>>(x, W1 + w1o, nullptr, nullptr,
            b1 + b1o, nullptr, nullptr, nullptr, hbuf, nullptr, nullptr, nullptr, 3072, 4 * CDIM, CDIM);
        gemm_k<1><<<dim3(12, 48, 1), 256, 0, stream>>>(hbuf, W2 + w1o, nullptr, nullptr,
            b2 + bo, nullptr, nullptr, x, x2, nullptr, nullptr, nullptr, 3072, CDIM, 4 * CDIM);
        ln_k<<<dim3(2 * T3), 256, 0, stream>>>(x2, x, ln2_g + bo, ln2_b + bo);
    }

    head_k<<<dim3(1024, 2), 64, 0, stream>>>(x, W_ps, b_ps, W_pa, b_pa, (float*)d_out);
}

// Round 2
// 1649.774 us; speedup vs baseline: 1.4958x; 1.4958x over previous
//
#include <hip/hip_runtime.h>

#define SEQ 512
#define T3 1536
#define CDIM 768
#define NH 12
#define HD 64
#define NL 6

typedef __attribute__((ext_vector_type(8))) short bh8;
typedef __attribute__((ext_vector_type(4))) short s4;
typedef __attribute__((ext_vector_type(4))) float f4;

__device__ inline short f2bf(float f) {
    union { float f; unsigned u; } x; x.f = f;
    unsigned r = x.u + 0x7FFFu + ((x.u >> 16) & 1u);
    return (short)(r >> 16);
}

__device__ inline void gload16(const void* g, void* l) {
    __builtin_amdgcn_global_load_lds(
        (const __attribute__((address_space(1))) unsigned int*)g,
        (__attribute__((address_space(3))) unsigned int*)l, 16, 0, 0);
}

__device__ inline float block_sum(float v, volatile float* red, int tid) {
    #pragma unroll
    for (int off = 32; off > 0; off >>= 1) v += __shfl_down(v, off, 64);
    __syncthreads();
    if ((tid & 63) == 0) red[tid >> 6] = v;
    __syncthreads();
    return red[0] + red[1] + red[2] + red[3];
}

// ---------------- transpose + f32->bf16 weight conversion ----------------
// in: W [K][N] f32 ; out: Wt [N][K] bf16
__global__ __launch_bounds__(256) void convT_k(const float* __restrict__ W, short* __restrict__ Wt,
                                               int K, int N) {
    __shared__ float t[32][33];
    int n0 = blockIdx.x * 32, k0 = blockIdx.y * 32;
    int tid = threadIdx.x;
    int r = tid >> 3, c4 = (tid & 7) * 4;
    f4 v = *(const f4*)(W + (size_t)(k0 + r) * N + n0 + c4);
    t[r][c4] = v[0]; t[r][c4 + 1] = v[1]; t[r][c4 + 2] = v[2]; t[r][c4 + 3] = v[3];
    __syncthreads();
    s4 o;
    o[0] = f2bf(t[c4 + 0][r]); o[1] = f2bf(t[c4 + 1][r]);
    o[2] = f2bf(t[c4 + 2][r]); o[3] = f2bf(t[c4 + 3][r]);
    *(s4*)(Wt + (size_t)(n0 + r) * K + k0 + c4) = o;
}

// ---------------- embedding + LN0 ----------------
__global__ __launch_bounds__(256) void embed_ln0_k(
        const float* __restrict__ states, const float* __restrict__ actions,
        const float* __restrict__ goals, const int* __restrict__ timesteps,
        const float* __restrict__ W_s, const float* __restrict__ b_s,
        const float* __restrict__ W_a, const float* __restrict__ b_a,
        const float* __restrict__ W_g, const float* __restrict__ b_g,
        const float* __restrict__ E_t, const float* __restrict__ g0,
        const float* __restrict__ bb0, float* __restrict__ x, short* __restrict__ xb) {
    int row = blockIdx.x;
    int b = row / T3, t3 = row - b * T3;
    int t = t3 / 3, kind = t3 - t * 3;
    __shared__ float inv[64];
    __shared__ float xr[CDIM];
    __shared__ float red[4];
    int tid = threadIdx.x;
    const float* src; const float* W; const float* bias;
    if (kind == 0)      { src = goals + b * 64;                       W = W_g; bias = b_g; }
    else if (kind == 1) { src = states + ((size_t)b * SEQ + t) * 64;  W = W_s; bias = b_s; }
    else                { src = actions + ((size_t)b * SEQ + t) * 64; W = W_a; bias = b_a; }
    if (tid < 64) inv[tid] = src[tid];
    __syncthreads();
    int ts = timesteps[b * SEQ + t];
    for (int c = tid; c < CDIM; c += 256) {
        float acc = bias[c] + E_t[(size_t)ts * CDIM + c];
        #pragma unroll 8
        for (int kk = 0; kk < 64; ++kk) acc += inv[kk] * W[kk * CDIM + c];
        xr[c] = acc;
    }
    __syncthreads();
    float v0 = xr[tid], v1 = xr[tid + 256], v2 = xr[tid + 512];
    float mean = block_sum(v0 + v1 + v2, red, tid) * (1.f / CDIM);
    float d0 = v0 - mean, d1 = v1 - mean, d2 = v2 - mean;
    float var = block_sum(d0 * d0 + d1 * d1 + d2 * d2, red, tid) * (1.f / CDIM);
    float rs = rsqrtf(var + 1e-5f);
    float* w = x + (size_t)row * CDIM;
    short* wb = xb + (size_t)row * CDIM;
    float o0 = d0 * rs * g0[tid]       + bb0[tid];
    float o1 = d1 * rs * g0[tid + 256] + bb0[tid + 256];
    float o2 = d2 * rs * g0[tid + 512] + bb0[tid + 512];
    w[tid] = o0; w[tid + 256] = o1; w[tid + 512] = o2;
    wb[tid] = f2bf(o0); wb[tid + 256] = f2bf(o1); wb[tid + 512] = f2bf(o2);
}

// ---------------- LayerNorm (f32 in -> f32 + bf16 out) ----------------
__global__ __launch_bounds__(256) void ln_k(const float* __restrict__ in, float* __restrict__ outp,
                                            short* __restrict__ outb,
                                            const float* __restrict__ g, const float* __restrict__ bb) {
    int row = blockIdx.x, tid = threadIdx.x;
    __shared__ float red[4];
    const float* r = in + (size_t)row * CDIM;
    float v0 = r[tid], v1 = r[tid + 256], v2 = r[tid + 512];
    float mean = block_sum(v0 + v1 + v2, red, tid) * (1.f / CDIM);
    float d0 = v0 - mean, d1 = v1 - mean, d2 = v2 - mean;
    float var = block_sum(d0 * d0 + d1 * d1 + d2 * d2, red, tid) * (1.f / CDIM);
    float rs = rsqrtf(var + 1e-5f);
    float* w = outp + (size_t)row * CDIM;
    short* wb = outb + (size_t)row * CDIM;
    float o0 = d0 * rs * g[tid]       + bb[tid];
    float o1 = d1 * rs * g[tid + 256] + bb[tid + 256];
    float o2 = d2 * rs * g[tid + 512] + bb[tid + 512];
    w[tid] = o0; w[tid + 256] = o1; w[tid + 512] = o2;
    wb[tid] = f2bf(o0); wb[tid + 256] = f2bf(o1); wb[tid + 512] = f2bf(o2);
}

// ---------------- 128x128 MFMA GEMM, bf16 in, global_load_lds staging ------
// A [M][K] bf16, B [N][K] bf16 (pre-transposed). M=3072.
// EPI 0: QKV -> bf16 scatter to [B,H,T3,D] (blockIdx.z selects q/k/v)
// EPI 1: outF = acc + bias + res (f32)
// EPI 2: outB0 = bf16(gelu(acc + bias))
template<int EPI>
__global__ __launch_bounds__(256) void gemm2_k(
        const short* __restrict__ A, const short* __restrict__ B0,
        const short* __restrict__ B1, const short* __restrict__ B2,
        const float* __restrict__ bias0, const float* __restrict__ bias1,
        const float* __restrict__ bias2, const float* __restrict__ res,
        float* __restrict__ outF, short* __restrict__ outQ,
        short* __restrict__ outK, short* __restrict__ outV,
        int N, int K) {
    const short* Bw = B0; const float* bias = bias0; short* outB = outQ;
    if (EPI == 0) {
        if (blockIdx.z == 1) { Bw = B1; bias = bias1; outB = outK; }
        else if (blockIdx.z == 2) { Bw = B2; bias = bias2; outB = outV; }
    }
    __shared__ short As[128 * 32];
    __shared__ short Bs[128 * 32];
    int tid = threadIdx.x;
    int lane = tid & 63, wave = tid >> 6;
    int wm = wave >> 1, wn = wave & 1;
    int lr = lane & 15, lg = lane >> 4;
    int bm = blockIdx.y * 128, bn = blockIdx.x * 128;
    int sr = lane >> 2, sc = (lane & 3) * 8;

    const short* pa[2]; const short* pb[2];
    short* la[2]; short* lb[2];
    #pragma unroll
    for (int j = 0; j < 2; ++j) {
        int q = wave * 2 + j;
        pa[j] = A  + (size_t)(bm + q * 16 + sr) * K + sc;
        pb[j] = Bw + (size_t)(bn + q * 16 + sr) * K + sc;
        la[j] = As + q * 512;
        lb[j] = Bs + q * 512;
    }

    f4 acc[4][4] = {};
    for (int k0 = 0; k0 < K; k0 += 32) {
        #pragma unroll
        for (int j = 0; j < 2; ++j) gload16(pa[j] + k0, la[j]);
        #pragma unroll
        for (int j = 0; j < 2; ++j) gload16(pb[j] + k0, lb[j]);
        __syncthreads();
        bh8 af[4], bfr[4];
        #pragma unroll
        for (int mi = 0; mi < 4; ++mi) af[mi] = *(const bh8*)(As + (wm * 64 + mi * 16 + lr) * 32 + lg * 8);
        #pragma unroll
        for (int ni = 0; ni < 4; ++ni) bfr[ni] = *(const bh8*)(Bs + (wn * 64 + ni * 16 + lr) * 32 + lg * 8);
        #pragma unroll
        for (int mi = 0; mi < 4; ++mi)
        #pragma unroll
        for (int ni = 0; ni < 4; ++ni)
            acc[mi][ni] = __builtin_amdgcn_mfma_f32_16x16x32_bf16(af[mi], bfr[ni], acc[mi][ni], 0, 0, 0);
        __syncthreads();
    }

    #pragma unroll
    for (int mi = 0; mi < 4; ++mi)
    #pragma unroll
    for (int ni = 0; ni < 4; ++ni)
    #pragma unroll
    for (int i = 0; i < 4; ++i) {
        int row = bm + wm * 64 + mi * 16 + lg * 4 + i;
        int col = bn + wn * 64 + ni * 16 + lr;
        float vv = acc[mi][ni][i] + bias[col];
        if (EPI == 0) {
            int b = row / T3, t = row - b * T3;
            int h = col >> 6, d = col & 63;
            outB[((((size_t)b * NH + h) * T3 + t) << 6) + d] = f2bf(vv);
        } else if (EPI == 1) {
            outF[(size_t)row * N + col] = vv + res[(size_t)row * N + col];
        } else {
            float gl = 0.5f * vv * (1.0f + erff(vv * 0.70710678118f));
            outQ[(size_t)row * N + col] = f2bf(gl);
        }
    }
}

// ---------------- causal flash attention (bf16 out) ----------------
__global__ __launch_bounds__(256) void attn_k(const short* __restrict__ q, const short* __restrict__ k,
                                              const short* __restrict__ v, short* __restrict__ att) {
    int qt = blockIdx.x;
    int bh = blockIdx.y;
    int b = bh / NH, h = bh - b * NH;
    const short* qb = q + (size_t)bh * T3 * HD;
    const short* kb = k + (size_t)bh * T3 * HD;
    const short* vb = v + (size_t)bh * T3 * HD;
    __shared__ short Kt[64][72];
    __shared__ short Vt[64][72];
    __shared__ short Pl[4][16][72];
    int tid = threadIdx.x, lane = tid & 63, wave = tid >> 6;
    int lr = lane & 15, lg = lane >> 4;
    int qrow0 = qt * 64 + wave * 16;
    bh8 aq0 = *(const bh8*)(qb + (size_t)(qrow0 + lr) * HD + lg * 8);
    bh8 aq1 = *(const bh8*)(qb + (size_t)(qrow0 + lr) * HD + 32 + lg * 8);
    f4 o[4] = {};
    float mrow[4], lrow[4];
    #pragma unroll
    for (int i = 0; i < 4; ++i) { mrow[i] = -1e30f; lrow[i] = 0.f; }
    int stok = tid >> 2, sd0 = (tid & 3) * 16;
    for (int kt = 0; kt <= qt; ++kt) {
        const short* ks = kb + (size_t)(kt * 64 + stok) * HD + sd0;
        bh8 kv0 = *(const bh8*)ks, kv1 = *(const bh8*)(ks + 8);
        *(bh8*)&Kt[stok][sd0]     = kv0;
        *(bh8*)&Kt[stok][sd0 + 8] = kv1;
        const short* vs = vb + (size_t)(kt * 64 + stok) * HD + sd0;
        bh8 vv0 = *(const bh8*)vs, vv1 = *(const bh8*)(vs + 8);
        #pragma unroll
        for (int i = 0; i < 8; ++i) { Vt[sd0 + i][stok] = vv0[i]; Vt[sd0 + 8 + i][stok] = vv1[i]; }
        __syncthreads();
        f4 s[4];
        #pragma unroll
        for (int nf = 0; nf < 4; ++nf) {
            bh8 bk0 = *(const bh8*)&Kt[nf * 16 + lr][lg * 8];
            bh8 bk1 = *(const bh8*)&Kt[nf * 16 + lr][32 + lg * 8];
            f4 t = {};
            t = __builtin_amdgcn_mfma_f32_16x16x32_bf16(aq0, bk0, t, 0, 0, 0);
            t = __builtin_amdgcn_mfma_f32_16x16x32_bf16(aq1, bk1, t, 0, 0, 0);
            #pragma unroll
            for (int i = 0; i < 4; ++i) s[nf][i] = t[i] * 0.125f;
        }
        if (kt == qt) {
            #pragma unroll
            for (int nf = 0; nf < 4; ++nf)
            #pragma unroll
            for (int i = 0; i < 4; ++i) {
                int qr = wave * 16 + lg * 4 + i;
                int tc = nf * 16 + lr;
                if (tc > qr) s[nf][i] = -1e30f;
            }
        }
        #pragma unroll
        for (int i = 0; i < 4; ++i) {
            float mt = fmaxf(fmaxf(s[0][i], s[1][i]), fmaxf(s[2][i], s[3][i]));
            #pragma unroll
            for (int off = 8; off > 0; off >>= 1) mt = fmaxf(mt, __shfl_xor(mt, off, 16));
            float mn = fmaxf(mrow[i], mt);
            float fs = expf(mrow[i] - mn);
            float ps = 0.f;
            #pragma unroll
            for (int nf = 0; nf < 4; ++nf) { float p = expf(s[nf][i] - mn); s[nf][i] = p; ps += p; }
            #pragma unroll
            for (int off = 8; off > 0; off >>= 1) ps += __shfl_xor(ps, off, 16);
            mrow[i] = mn;
            lrow[i] = lrow[i] * fs + ps;
            #pragma unroll
            for (int nf = 0; nf < 4; ++nf) o[nf][i] *= fs;
            #pragma unroll
            for (int nf = 0; nf < 4; ++nf) Pl[wave][lg * 4 + i][nf * 16 + lr] = f2bf(s[nf][i]);
        }
        #pragma unroll
        for (int nf = 0; nf < 4; ++nf) {
            #pragma unroll
            for (int kk = 0; kk < 2; ++kk) {
                bh8 ap = *(const bh8*)&Pl[wave][lr][kk * 32 + lg * 8];
                bh8 bv = *(const bh8*)&Vt[nf * 16 + lr][kk * 32 + lg * 8];
                o[nf] = __builtin_amdgcn_mfma_f32_16x16x32_bf16(ap, bv, o[nf], 0, 0, 0);
            }
        }
        __syncthreads();
    }
    #pragma unroll
    for (int nf = 0; nf < 4; ++nf)
    #pragma unroll
    for (int i = 0; i < 4; ++i) {
        int qrow = qrow0 + lg * 4 + i;
        int d = nf * 16 + lr;
        att[((size_t)b * T3 + qrow) * CDIM + h * 64 + d] = f2bf(o[nf][i] / lrow[i]);
    }
}

// ---------------- output heads ----------------
__global__ __launch_bounds__(64) void head_k(const float* __restrict__ x,
                                             const float* __restrict__ Wps, const float* __restrict__ bps,
                                             const float* __restrict__ Wpa, const float* __restrict__ bpa,
                                             float* __restrict__ out) {
    int o = blockIdx.y;
    int bs = blockIdx.x;
    int b = bs >> 9, t = bs & 511;
    int kind = (o == 0) ? 2 : 1;
    const float* W = (o == 0) ? Wps : Wpa;
    const float* bi = (o == 0) ? bps : bpa;
    const float* xr = x + ((size_t)b * T3 + t * 3 + kind) * CDIM;
    int n = threadIdx.x;
    float a0 = 0.f, a1 = 0.f, a2 = 0.f, a3 = 0.f;
    for (int kk = 0; kk < CDIM; kk += 4) {
        a0 = fmaf(xr[kk],     W[(kk)     * 64 + n], a0);
        a1 = fmaf(xr[kk + 1], W[(kk + 1) * 64 + n], a1);
        a2 = fmaf(xr[kk + 2], W[(kk + 2) * 64 + n], a2);
        a3 = fmaf(xr[kk + 3], W[(kk + 3) * 64 + n], a3);
    }
    float acc = bi[n] + ((a0 + a1) + (a2 + a3));
    if (o == 1) acc = tanhf(acc);
    out[(((size_t)o * 2 + b) * SEQ + t) * 64 + n] = acc;
}

extern "C" void kernel_launch(void* const* d_in, const int* in_sizes, int n_in,
                              void* d_out, int out_size, void* d_ws, size_t ws_size,
                              hipStream_t stream) {
    const float* states    = (const float*)d_in[0];
    const float* actions   = (const float*)d_in[1];
    const float* goals     = (const float*)d_in[2];
    const int*   timesteps = (const int*)d_in[4];
    const float* W_s = (const float*)d_in[5];  const float* b_s = (const float*)d_in[6];
    const float* W_a = (const float*)d_in[7];  const float* b_a = (const float*)d_in[8];
    const float* W_g = (const float*)d_in[9];  const float* b_g = (const float*)d_in[10];
    const float* E_t = (const float*)d_in[11];
    const float* ln0_g = (const float*)d_in[12]; const float* ln0_b = (const float*)d_in[13];
    const float* Wq = (const float*)d_in[14]; const float* bq = (const float*)d_in[15];
    const float* Wk = (const float*)d_in[16]; const float* bk = (const float*)d_in[17];
    const float* Wv = (const float*)d_in[18]; const float* bv = (const float*)d_in[19];
    const float* Wp = (const float*)d_in[20]; const float* bp = (const float*)d_in[21];
    const float* ln1_g = (const float*)d_in[22]; const float* ln1_b = (const float*)d_in[23];
    const float* W1 = (const float*)d_in[24]; const float* b1 = (const float*)d_in[25];
    const float* W2 = (const float*)d_in[26]; const float* b2 = (const float*)d_in[27];
    const float* ln2_g = (const float*)d_in[28]; const float* ln2_b = (const float*)d_in[29];
    const float* W_ps = (const float*)d_in[30]; const float* b_ps = (const float*)d_in[31];
    const float* W_pa = (const float*)d_in[32]; const float* b_pa = (const float*)d_in[33];

    char* ws = (char*)d_ws;
    float* x_f   = (float*)(ws);                    //  9.44 MB [3072][768] f32 residual
    float* x2_f  = (float*)(ws + 9437184);          //  9.44 MB
    short* x_bf  = (short*)(ws + 18874368);         //  4.72 MB [3072][768] bf16
    short* attb  = (short*)(ws + 23592960);         //  4.72 MB
    short* h_bf  = (short*)(ws + 28311552);         // 18.87 MB [3072][3072] bf16
    short* qb    = (short*)(ws + 47185920);         //  4.72 MB [B,H,T3,D] bf16
    short* kb    = (short*)(ws + 51904512);
    short* vb    = (short*)(ws + 56623104);
    short* Wqt   = (short*)(ws + 61341696);         //  1.18 MB [768][768] bf16
    short* Wkt   = (short*)(ws + 62521344);
    short* Wvt   = (short*)(ws + 63700992);
    short* Wpt   = (short*)(ws + 64880640);
    short* W1t   = (short*)(ws + 66060288);         //  4.72 MB [3072][768]
    short* W2t   = (short*)(ws + 70778880);         //  4.72 MB [768][3072]

    embed_ln0_k<<<dim3(2 * T3), 256, 0, stream>>>(states, actions, goals, timesteps,
        W_s, b_s, W_a, b_a, W_g, b_g, E_t, ln0_g, ln0_b, x_f, x_bf);

    for (int l = 0; l < NL; ++l) {
        size_t wo = (size_t)l * CDIM * CDIM, bo = (size_t)l * CDIM;
        size_t w1o = (size_t)l * CDIM * 4 * CDIM, b1o = (size_t)l * 4 * CDIM;
        convT_k<<<dim3(24, 24), 256, 0, stream>>>(Wq + wo, Wqt, CDIM, CDIM);
        convT_k<<<dim3(24, 24), 256, 0, stream>>>(Wk + wo, Wkt, CDIM, CDIM);
        convT_k<<<dim3(24, 24), 256, 0, stream>>>(Wv + wo, Wvt, CDIM, CDIM);
        convT_k<<<dim3(24, 24), 256, 0, stream>>>(Wp + wo, Wpt, CDIM, CDIM);
        convT_k<<<dim3(96, 24), 256, 0, stream>>>(W1 + w1o, W1t, CDIM, 4 * CDIM);
        convT_k<<<dim3(24, 96), 256, 0, stream>>>(W2 + w1o, W2t, 4 * CDIM, CDIM);

        gemm2_k<0><<<dim3(6, 24, 3), 256, 0, stream>>>(x_bf, Wqt, Wkt, Wvt,
            bq + bo, bk + bo, bv + bo, nullptr, nullptr, qb, kb, vb, CDIM, CDIM);
        attn_k<<<dim3(24, 24), 256, 0, stream>>>(qb, kb, vb, attb);
        gemm2_k<1><<<dim3(6, 24, 1), 256, 0, stream>>>(attb, Wpt, nullptr, nullptr,
            bp + bo, nullptr, nullptr, x_f, x2_f, nullptr, nullptr, nullptr, CDIM, CDIM);
        ln_k<<<dim3(2 * T3), 256, 0, stream>>>(x2_f, x_f, x_bf, ln1_g + bo, ln1_b + bo);
        gemm2_k<2><<<dim3(24, 24, 1), 256, 0, stream>>>(x_bf, W1t, nullptr, nullptr,
            b1 + b1o, nullptr, nullptr, nullptr, nullptr, h_bf, nullptr, nullptr, 4 * CDIM, CDIM);
        gemm2_k<1><<<dim3(6, 24, 1), 256, 0, stream>>>(h_bf, W2t, nullptr, nullptr,
            b2 + bo, nullptr, nullptr, x_f, x2_f, nullptr, nullptr, nullptr, CDIM, 4 * CDIM);
        ln_k<<<dim3(2 * T3), 256, 0, stream>>>(x2_f, x_f, x_bf, ln2_g + bo, ln2_b + bo);
    }

    head_k<<<dim3(1024, 2), 64, 0, stream>>>(x_f, W_ps, b_ps, W_pa, b_pa, (float*)d_out);
}

// Round 3
// 1184.364 us; speedup vs baseline: 2.0836x; 1.3930x over previous
//
#include <hip/hip_runtime.h>

#define SEQ 512
#define T3 1536
#define CDIM 768
#define NH 12
#define HD 64
#define NL 6

typedef __attribute__((ext_vector_type(8))) short bh8;
typedef __attribute__((ext_vector_type(4))) short s4;
typedef __attribute__((ext_vector_type(4))) float f4;

__device__ inline short f2bf(float f) {
    union { float f; unsigned u; } x; x.f = f;
    unsigned r = x.u + 0x7FFFu + ((x.u >> 16) & 1u);
    return (short)(r >> 16);
}

__device__ inline void gload16(const short* g, const short* l) {
    __builtin_amdgcn_global_load_lds(
        (const __attribute__((address_space(1))) unsigned int*)g,
        (__attribute__((address_space(3))) unsigned int*)l, 16, 0, 0);
}

__device__ inline float block_sum(float v, volatile float* red, int tid) {
    #pragma unroll
    for (int off = 32; off > 0; off >>= 1) v += __shfl_down(v, off, 64);
    __syncthreads();
    if ((tid & 63) == 0) red[tid >> 6] = v;
    __syncthreads();
    return red[0] + red[1] + red[2] + red[3];
}

// ---------------- all-weights transpose + bf16 conversion ----------------
// per layer (6912 tiles): Wq,Wk,Wv,Wp (768x768) -> [768][768], W1 (768x3072)
// -> [3072][768], W2 (3072x768) -> [768][3072]; dst els offsets:
// q 0, k 589824, v 1179648, p 1769472, W1t 2359296, W2t 4718592 (total 7077888)
__global__ __launch_bounds__(256) void convall_k(
        const float* __restrict__ Wq, const float* __restrict__ Wk,
        const float* __restrict__ Wv, const float* __restrict__ Wp,
        const float* __restrict__ W1, const float* __restrict__ W2,
        short* __restrict__ dst, int l0, long long dstStride) {
    int flat = blockIdx.x;
    int lrel = flat / 6912, r = flat - lrel * 6912;
    int l = l0 + lrel;
    short* base = dst + (long long)lrel * dstStride;
    const float* src; short* d; int K, N, tk, tn;
    if (r < 2304) {
        int mat = r / 576, t = r - mat * 576;
        tn = t % 24; tk = t / 24; K = 768; N = 768;
        const float* srcs[4] = {Wq, Wk, Wv, Wp};
        src = srcs[mat] + (size_t)l * 589824;
        d = base + mat * 589824;
    } else if (r < 4608) {
        int t = r - 2304; tn = t % 96; tk = t / 96; K = 768; N = 3072;
        src = W1 + (size_t)l * 2359296; d = base + 2359296;
    } else {
        int t = r - 4608; tn = t % 24; tk = t / 24; K = 3072; N = 768;
        src = W2 + (size_t)l * 2359296; d = base + 4718592;
    }
    __shared__ float tt[32][33];
    int tid = threadIdx.x, rr = tid >> 3, c4 = (tid & 7) * 4;
    int n0 = tn * 32, k0 = tk * 32;
    f4 v = *(const f4*)(src + (size_t)(k0 + rr) * N + n0 + c4);
    tt[rr][c4] = v[0]; tt[rr][c4 + 1] = v[1]; tt[rr][c4 + 2] = v[2]; tt[rr][c4 + 3] = v[3];
    __syncthreads();
    s4 o;
    o[0] = f2bf(tt[c4 + 0][rr]); o[1] = f2bf(tt[c4 + 1][rr]);
    o[2] = f2bf(tt[c4 + 2][rr]); o[3] = f2bf(tt[c4 + 3][rr]);
    *(s4*)(d + (size_t)(n0 + rr) * K + k0 + c4) = o;
}

// ---------------- embedding + LN0 ----------------
__global__ __launch_bounds__(256) void embed_ln0_k(
        const float* __restrict__ states, const float* __restrict__ actions,
        const float* __restrict__ goals, const int* __restrict__ timesteps,
        const float* __restrict__ W_s, const float* __restrict__ b_s,
        const float* __restrict__ W_a, const float* __restrict__ b_a,
        const float* __restrict__ W_g, const float* __restrict__ b_g,
        const float* __restrict__ E_t, const float* __restrict__ g0,
        const float* __restrict__ bb0, float* __restrict__ x, short* __restrict__ xb) {
    int row = blockIdx.x;
    int b = row / T3, t3 = row - b * T3;
    int t = t3 / 3, kind = t3 - t * 3;
    __shared__ float inv[64];
    __shared__ float xr[CDIM];
    __shared__ float red[4];
    int tid = threadIdx.x;
    const float* src; const float* W; const float* bias;
    if (kind == 0)      { src = goals + b * 64;                       W = W_g; bias = b_g; }
    else if (kind == 1) { src = states + ((size_t)b * SEQ + t) * 64;  W = W_s; bias = b_s; }
    else                { src = actions + ((size_t)b * SEQ + t) * 64; W = W_a; bias = b_a; }
    if (tid < 64) inv[tid] = src[tid];
    __syncthreads();
    int ts = timesteps[b * SEQ + t];
    for (int c = tid; c < CDIM; c += 256) {
        float acc = bias[c] + E_t[(size_t)ts * CDIM + c];
        #pragma unroll 8
        for (int kk = 0; kk < 64; ++kk) acc += inv[kk] * W[kk * CDIM + c];
        xr[c] = acc;
    }
    __syncthreads();
    float v0 = xr[tid], v1 = xr[tid + 256], v2 = xr[tid + 512];
    float mean = block_sum(v0 + v1 + v2, red, tid) * (1.f / CDIM);
    float d0 = v0 - mean, d1 = v1 - mean, d2 = v2 - mean;
    float var = block_sum(d0 * d0 + d1 * d1 + d2 * d2, red, tid) * (1.f / CDIM);
    float rs = rsqrtf(var + 1e-5f);
    float* w = x + (size_t)row * CDIM;
    short* wb = xb + (size_t)row * CDIM;
    float o0 = d0 * rs * g0[tid]       + bb0[tid];
    float o1 = d1 * rs * g0[tid + 256] + bb0[tid + 256];
    float o2 = d2 * rs * g0[tid + 512] + bb0[tid + 512];
    w[tid] = o0; w[tid + 256] = o1; w[tid + 512] = o2;
    wb[tid] = f2bf(o0); wb[tid + 256] = f2bf(o1); wb[tid + 512] = f2bf(o2);
}

// ---------------- LayerNorm (f32 in -> f32 + bf16 out) ----------------
__global__ __launch_bounds__(256) void ln_k(const float* __restrict__ in, float* __restrict__ outp,
                                            short* __restrict__ outb,
                                            const float* __restrict__ g, const float* __restrict__ bb) {
    int row = blockIdx.x, tid = threadIdx.x;
    __shared__ float red[4];
    const float* r = in + (size_t)row * CDIM;
    float v0 = r[tid], v1 = r[tid + 256], v2 = r[tid + 512];
    float mean = block_sum(v0 + v1 + v2, red, tid) * (1.f / CDIM);
    float d0 = v0 - mean, d1 = v1 - mean, d2 = v2 - mean;
    float var = block_sum(d0 * d0 + d1 * d1 + d2 * d2, red, tid) * (1.f / CDIM);
    float rs = rsqrtf(var + 1e-5f);
    float* w = outp + (size_t)row * CDIM;
    short* wb = outb + (size_t)row * CDIM;
    float o0 = d0 * rs * g[tid]       + bb[tid];
    float o1 = d1 * rs * g[tid + 256] + bb[tid + 256];
    float o2 = d2 * rs * g[tid + 512] + bb[tid + 512];
    w[tid] = o0; w[tid + 256] = o1; w[tid + 512] = o2;
    wb[tid] = f2bf(o0); wb[tid + 256] = f2bf(o1); wb[tid + 512] = f2bf(o2);
}

// ---------------- BMx128 MFMA GEMM, BK=64, swizzled LDS, gload staging ------
// A [M][K] bf16, B [N][K] bf16. EPI 0: QKV scatter (z: 0=Q,1=K,2=V^T)
// EPI 1: outF = acc + bias + res (f32);  EPI 2: outQ = bf16(gelu(acc+bias))
template<int BM, int EPI>
__global__ __launch_bounds__(256) void gemm3_k(
        const short* __restrict__ A, const short* __restrict__ B0,
        const short* __restrict__ B1, const short* __restrict__ B2,
        const float* __restrict__ bias0, const float* __restrict__ bias1,
        const float* __restrict__ bias2, const float* __restrict__ res,
        float* __restrict__ outF, short* __restrict__ outQ,
        short* __restrict__ outK, short* __restrict__ outV,
        int N, int K) {
    const short* Bw = B0; const float* bias = bias0; short* outB = outQ;
    int zid = 0;
    if (EPI == 0) {
        zid = blockIdx.z;
        if (zid == 1) { Bw = B1; bias = bias1; outB = outK; }
        else if (zid == 2) { Bw = B2; bias = bias2; outB = outV; }
    }
    __shared__ short As[BM * 64];
    __shared__ short Bs[128 * 64];
    int tid = threadIdx.x, lane = tid & 63, wave = tid >> 6;
    int wm = wave >> 1, wn = wave & 1, lr = lane & 15, lg = lane >> 4;
    int bm = blockIdx.y * BM, bn = blockIdx.x * 128;
    int rl = lane >> 3, ch = (lane & 7) ^ rl;
    constexpr int MI = BM / 32;
    f4 acc[MI][4] = {};
    for (int k0 = 0; k0 < K; k0 += 64) {
        #pragma unroll
        for (int j = 0; j < BM / 32; ++j)
            gload16(A + (size_t)(bm + wave * (BM / 4) + j * 8 + rl) * K + k0 + ch * 8,
                    As + (wave * (BM / 4) + j * 8) * 64);
        #pragma unroll
        for (int j = 0; j < 4; ++j)
            gload16(Bw + (size_t)(bn + wave * 32 + j * 8 + rl) * K + k0 + ch * 8,
                    Bs + (wave * 32 + j * 8) * 64);
        __syncthreads();
        bh8 af[MI][2], bf[4][2];
        #pragma unroll
        for (int mi = 0; mi < MI; ++mi)
        #pragma unroll
        for (int kk = 0; kk < 2; ++kk) {
            int m = wm * (BM / 2) + mi * 16 + lr;
            af[mi][kk] = *(const bh8*)(As + m * 64 + (((kk * 4 + lg) ^ (lr & 7)) * 8));
        }
        #pragma unroll
        for (int ni = 0; ni < 4; ++ni)
        #pragma unroll
        for (int kk = 0; kk < 2; ++kk) {
            int n = wn * 64 + ni * 16 + lr;
            bf[ni][kk] = *(const bh8*)(Bs + n * 64 + (((kk * 4 + lg) ^ (lr & 7)) * 8));
        }
        #pragma unroll
        for (int kk = 0; kk < 2; ++kk)
        #pragma unroll
        for (int mi = 0; mi < MI; ++mi)
        #pragma unroll
        for (int ni = 0; ni < 4; ++ni)
            acc[mi][ni] = __builtin_amdgcn_mfma_f32_16x16x32_bf16(af[mi][kk], bf[ni][kk], acc[mi][ni], 0, 0, 0);
        __syncthreads();
    }
    #pragma unroll
    for (int mi = 0; mi < MI; ++mi)
    #pragma unroll
    for (int ni = 0; ni < 4; ++ni)
    #pragma unroll
    for (int i = 0; i < 4; ++i) {
        int row = bm + wm * (BM / 2) + mi * 16 + lg * 4 + i;
        int col = bn + wn * 64 + ni * 16 + lr;
        float vv = acc[mi][ni][i] + bias[col];
        if (EPI == 0) {
            int b = row / T3, t = row - b * T3;
            int h = col >> 6, d = col & 63;
            if (zid == 2) outB[((size_t)(b * NH + h) * 64 + d) * T3 + t] = f2bf(vv);
            else          outB[((((size_t)b * NH + h) * T3 + t) << 6) + d] = f2bf(vv);
        } else if (EPI == 1) {
            outF[(size_t)row * N + col] = vv + res[(size_t)row * N + col];
        } else {
            float gl = 0.5f * vv * (1.0f + erff(vv * 0.70710678118f));
            outQ[(size_t)row * N + col] = f2bf(gl);
        }
    }
}

// ---------------- causal flash attention (no-max softmax, dbuf gload) -------
// q,k: [bh][T3][64] bf16 ; vt: [bh][64][T3] bf16 (pre-transposed by QKV gemm)
__global__ __launch_bounds__(256) void attn_k(const short* __restrict__ q, const short* __restrict__ k,
                                              const short* __restrict__ vt, short* __restrict__ att) {
    int idx = blockIdx.x;
    int qt = 23 - (idx / 24);          // heavy-first ordering
    int bh = idx % 24;
    int b = bh / NH, h = bh - b * NH;
    const short* qb = q  + (size_t)bh * T3 * HD;
    const short* kb = k  + (size_t)bh * T3 * HD;
    const short* vb = vt + (size_t)bh * HD * T3;
    __shared__ short Ks[2][4096];
    __shared__ short Vs[2][4096];
    __shared__ short Pl[4][16][72];
    int tid = threadIdx.x, lane = tid & 63, wave = tid >> 6;
    int lr = lane & 15, lg = lane >> 4;
    int rl = lane >> 3, ch = (lane & 7) ^ rl;
    int qrow0 = qt * 64 + wave * 16;
    bh8 aq0 = *(const bh8*)(qb + (size_t)(qrow0 + lr) * HD + lg * 8);
    bh8 aq1 = *(const bh8*)(qb + (size_t)(qrow0 + lr) * HD + 32 + lg * 8);
    f4 o[4] = {};
    float lsum[4] = {0.f, 0.f, 0.f, 0.f};

    auto STAGE = [&](int kt2, int buf) {
        const short* kb2 = kb + (size_t)kt2 * 64 * HD;
        #pragma unroll
        for (int j = 0; j < 2; ++j)
            gload16(kb2 + (wave * 16 + j * 8 + rl) * HD + ch * 8,
                    &Ks[buf][(wave * 16 + j * 8) * 64]);
        const short* vb2 = vb + kt2 * 64;
        #pragma unroll
        for (int j = 0; j < 2; ++j)
            gload16(vb2 + (size_t)(wave * 16 + j * 8 + rl) * T3 + ch * 8,
                    &Vs[buf][(wave * 16 + j * 8) * 64]);
    };

    STAGE(0, 0);
    int cur = 0;
    for (int kt = 0; kt <= qt; ++kt) {
        if (kt < qt) {
            STAGE(kt + 1, cur ^ 1);
            asm volatile("s_waitcnt vmcnt(4)" ::: "memory");
        } else {
            asm volatile("s_waitcnt vmcnt(0)" ::: "memory");
        }
        __builtin_amdgcn_s_barrier();
        __builtin_amdgcn_sched_barrier(0);
        const short* Kb = &Ks[cur][0];
        const short* Vb = &Vs[cur][0];
        f4 s[4];
        #pragma unroll
        for (int nf = 0; nf < 4; ++nf) {
            int tok = nf * 16 + lr;
            bh8 bk0 = *(const bh8*)(Kb + tok * 64 + ((lg ^ (lr & 7)) * 8));
            bh8 bk1 = *(const bh8*)(Kb + tok * 64 + (((4 + lg) ^ (lr & 7)) * 8));
            f4 t = {};
            t = __builtin_amdgcn_mfma_f32_16x16x32_bf16(aq0, bk0, t, 0, 0, 0);
            t = __builtin_amdgcn_mfma_f32_16x16x32_bf16(aq1, bk1, t, 0, 0, 0);
            s[nf] = t;
        }
        #pragma unroll
        for (int nf = 0; nf < 4; ++nf)
        #pragma unroll
        for (int i = 0; i < 4; ++i) {
            float p = __expf(s[nf][i] * 0.125f);
            if (kt == qt && (nf * 16 + lr) > (wave * 16 + lg * 4 + i)) p = 0.f;
            lsum[i] += p;
            Pl[wave][lg * 4 + i][nf * 16 + lr] = f2bf(p);
        }
        bh8 ap0 = *(const bh8*)&Pl[wave][lr][lg * 8];
        bh8 ap1 = *(const bh8*)&Pl[wave][lr][32 + lg * 8];
        #pragma unroll
        for (int nf = 0; nf < 4; ++nf) {
            int d = nf * 16 + lr;
            bh8 bv0 = *(const bh8*)(Vb + d * 64 + ((lg ^ (lr & 7)) * 8));
            bh8 bv1 = *(const bh8*)(Vb + d * 64 + (((4 + lg) ^ (lr & 7)) * 8));
            o[nf] = __builtin_amdgcn_mfma_f32_16x16x32_bf16(ap0, bv0, o[nf], 0, 0, 0);
            o[nf] = __builtin_amdgcn_mfma_f32_16x16x32_bf16(ap1, bv1, o[nf], 0, 0, 0);
        }
        __builtin_amdgcn_sched_barrier(0);
        __builtin_amdgcn_s_barrier();
        cur ^= 1;
    }
    float linv[4];
    #pragma unroll
    for (int i = 0; i < 4; ++i) {
        float l = lsum[i];
        #pragma unroll
        for (int off = 1; off < 16; off <<= 1) l += __shfl_xor(l, off, 16);
        linv[i] = 1.f / l;
    }
    #pragma unroll
    for (int nf = 0; nf < 4; ++nf)
    #pragma unroll
    for (int i = 0; i < 4; ++i) {
        int qrow = qrow0 + lg * 4 + i;
        att[((size_t)b * T3 + qrow) * CDIM + h * 64 + nf * 16 + lr] = f2bf(o[nf][i] * linv[i]);
    }
}

// ---------------- output heads ----------------
__global__ __launch_bounds__(64) void head_k(const float* __restrict__ x,
                                             const float* __restrict__ Wps, const float* __restrict__ bps,
                                             const float* __restrict__ Wpa, const float* __restrict__ bpa,
                                             float* __restrict__ out) {
    int o = blockIdx.y;
    int bs = blockIdx.x;
    int b = bs >> 9, t = bs & 511;
    int kind = (o == 0) ? 2 : 1;
    const float* W = (o == 0) ? Wps : Wpa;
    const float* bi = (o == 0) ? bps : bpa;
    const float* xr = x + ((size_t)b * T3 + t * 3 + kind) * CDIM;
    int n = threadIdx.x;
    float a0 = 0.f, a1 = 0.f, a2 = 0.f, a3 = 0.f;
    for (int kk = 0; kk < CDIM; kk += 4) {
        a0 = fmaf(xr[kk],     W[(kk)     * 64 + n], a0);
        a1 = fmaf(xr[kk + 1], W[(kk + 1) * 64 + n], a1);
        a2 = fmaf(xr[kk + 2], W[(kk + 2) * 64 + n], a2);
        a3 = fmaf(xr[kk + 3], W[(kk + 3) * 64 + n], a3);
    }
    float acc = bi[n] + ((a0 + a1) + (a2 + a3));
    if (o == 1) acc = tanhf(acc);
    out[(((size_t)o * 2 + b) * SEQ + t) * 64 + n] = acc;
}

extern "C" void kernel_launch(void* const* d_in, const int* in_sizes, int n_in,
                              void* d_out, int out_size, void* d_ws, size_t ws_size,
                              hipStream_t stream) {
    const float* states    = (const float*)d_in[0];
    const float* actions   = (const float*)d_in[1];
    const float* goals     = (const float*)d_in[2];
    const int*   timesteps = (const int*)d_in[4];
    const float* W_s = (const float*)d_in[5];  const float* b_s = (const float*)d_in[6];
    const float* W_a = (const float*)d_in[7];  const float* b_a = (const float*)d_in[8];
    const float* W_g = (const float*)d_in[9];  const float* b_g = (const float*)d_in[10];
    const float* E_t = (const float*)d_in[11];
    const float* ln0_g = (const float*)d_in[12]; const float* ln0_b = (const float*)d_in[13];
    const float* Wq = (const float*)d_in[14]; const float* bq = (const float*)d_in[15];
    const float* Wk = (const float*)d_in[16]; const float* bk = (const float*)d_in[17];
    const float* Wv = (const float*)d_in[18]; const float* bv = (const float*)d_in[19];
    const float* Wp = (const float*)d_in[20]; const float* bp = (const float*)d_in[21];
    const float* ln1_g = (const float*)d_in[22]; const float* ln1_b = (const float*)d_in[23];
    const float* W1 = (const float*)d_in[24]; const float* b1 = (const float*)d_in[25];
    const float* W2 = (const float*)d_in[26]; const float* b2 = (const float*)d_in[27];
    const float* ln2_g = (const float*)d_in[28]; const float* ln2_b = (const float*)d_in[29];
    const float* W_ps = (const float*)d_in[30]; const float* b_ps = (const float*)d_in[31];
    const float* W_pa = (const float*)d_in[32]; const float* b_pa = (const float*)d_in[33];

    char* ws = (char*)d_ws;
    float* x_f   = (float*)(ws);                    //  9.44 MB [3072][768] f32 residual
    float* x2_f  = (float*)(ws + 9437184);          //  9.44 MB
    short* x_bf  = (short*)(ws + 18874368);         //  4.72 MB [3072][768] bf16
    short* attb  = (short*)(ws + 23592960);         //  4.72 MB
    short* h_bf  = (short*)(ws + 28311552);         // 18.87 MB [3072][3072] bf16
    short* qb    = (short*)(ws + 47185920);         //  4.72 MB [B,H,T3,D] bf16
    short* kb    = (short*)(ws + 51904512);         //  4.72 MB [B,H,T3,D]
    short* vbt   = (short*)(ws + 56623104);         //  4.72 MB [B,H,D,T3]
    short* wts   = (short*)(ws + 61341696);         // per-layer 14.16 MB or all 84.9 MB

    const long long WL = 7077888;                   // els per layer in wts
    bool allw = ws_size >= 146276352ull;

    embed_ln0_k<<<dim3(2 * T3), 256, 0, stream>>>(states, actions, goals, timesteps,
        W_s, b_s, W_a, b_a, W_g, b_g, E_t, ln0_g, ln0_b, x_f, x_bf);

    if (allw)
        convall_k<<<dim3(6912 * NL), 256, 0, stream>>>(Wq, Wk, Wv, Wp, W1, W2, wts, 0, WL);

    for (int l = 0; l < NL; ++l) {
        size_t bo = (size_t)l * CDIM, b1o = (size_t)l * 4 * CDIM;
        if (!allw)
            convall_k<<<dim3(6912), 256, 0, stream>>>(Wq, Wk, Wv, Wp, W1, W2, wts, l, 0);
        short* wb  = wts + (allw ? (long long)l * WL : 0);
        short* Wqt = wb;
        short* Wkt = wb + 589824;
        short* Wvt = wb + 1179648;
        short* Wpt = wb + 1769472;
        short* W1t = wb + 2359296;
        short* W2t = wb + 4718592;

        gemm3_k<128, 0><<<dim3(6, 24, 3), 256, 0, stream>>>(x_bf, Wqt, Wkt, Wvt,
            bq + bo, bk + bo, bv + bo, nullptr, nullptr, qb, kb, vbt, CDIM, CDIM);
        attn_k<<<dim3(576), 256, 0, stream>>>(qb, kb, vbt, attb);
        gemm3_k<64, 1><<<dim3(6, 48, 1), 256, 0, stream>>>(attb, Wpt, nullptr, nullptr,
            bp + bo, nullptr, nullptr, x_f, x2_f, nullptr, nullptr, nullptr, CDIM, CDIM);
        ln_k<<<dim3(2 * T3), 256, 0, stream>>>(x2_f, x_f, x_bf, ln1_g + bo, ln1_b + bo);
        gemm3_k<128, 2><<<dim3(24, 24, 1), 256, 0, stream>>>(x_bf, W1t, nullptr, nullptr,
            b1 + b1o, nullptr, nullptr, nullptr, nullptr, h_bf, nullptr, nullptr, 4 * CDIM, CDIM);
        gemm3_k<64, 1><<<dim3(6, 48, 1), 256, 0, stream>>>(h_bf, W2t, nullptr, nullptr,
            b2 + bo, nullptr, nullptr, x_f, x2_f, nullptr, nullptr, nullptr, CDIM, 4 * CDIM);
        ln_k<<<dim3(2 * T3), 256, 0, stream>>>(x2_f, x_f, x_bf, ln2_g + bo, ln2_b + bo);
    }

    head_k<<<dim3(1024, 2), 64, 0, stream>>>(x_f, W_ps, b_ps, W_pa, b_pa, (float*)d_out);
}

// Round 4
// 1175.549 us; speedup vs baseline: 2.0993x; 1.0075x over previous
//
#include <hip/hip_runtime.h>

#define SEQ 512
#define T3 1536
#define CDIM 768
#define NH 12
#define HD 64
#define NL 6

typedef __attribute__((ext_vector_type(8))) short bh8;
typedef __attribute__((ext_vector_type(4))) short s4;
typedef __attribute__((ext_vector_type(4))) float f4;

__device__ inline short f2bf(float f) {
    union { float f; unsigned u; } x; x.f = f;
    unsigned r = x.u + 0x7FFFu + ((x.u >> 16) & 1u);
    return (short)(r >> 16);
}

__device__ inline void gload16(const short* g, const short* l) {
    __builtin_amdgcn_global_load_lds(
        (const __attribute__((address_space(1))) unsigned int*)g,
        (__attribute__((address_space(3))) unsigned int*)l, 16, 0, 0);
}

__device__ inline float block_sum(float v, volatile float* red, int tid) {
    #pragma unroll
    for (int off = 32; off > 0; off >>= 1) v += __shfl_down(v, off, 64);
    __syncthreads();
    if ((tid & 63) == 0) red[tid >> 6] = v;
    __syncthreads();
    return red[0] + red[1] + red[2] + red[3];
}

// ---------------- per-layer weight transpose + bf16 conversion -------------
// 64x64 f32 tiles, full-line reads AND writes.
// dst els offsets: q 0, k 589824, v 1179648, p 1769472, W1t 2359296,
// W2t 4718592 (total 7077888 els per layer)
__global__ __launch_bounds__(256) void conv64_k(
        const float* __restrict__ Wq, const float* __restrict__ Wk,
        const float* __restrict__ Wv, const float* __restrict__ Wp,
        const float* __restrict__ W1, const float* __restrict__ W2,
        short* __restrict__ dst, int l) {
    int r = blockIdx.x;
    const float* src; short* d; int K, N, tk, tn;
    if (r < 576) {
        int mat = r / 144, t = r - mat * 144;
        tk = t / 12; tn = t % 12; K = 768; N = 768;
        const float* srcs[4] = {Wq, Wk, Wv, Wp};
        src = srcs[mat] + (size_t)l * 589824;
        d = dst + mat * 589824;
    } else if (r < 1152) {
        int t = r - 576; tk = t / 48; tn = t % 48; K = 768; N = 3072;
        src = W1 + (size_t)l * 2359296; d = dst + 2359296;
    } else {
        int t = r - 1152; tk = t / 12; tn = t % 12; K = 3072; N = 768;
        src = W2 + (size_t)l * 2359296; d = dst + 4718592;
    }
    int k0 = tk * 64, n0 = tn * 64;
    __shared__ float t2[64][65];      // [n][k]
    int tid = threadIdx.x;
    int rk = tid >> 4, cn4 = (tid & 15) * 4;
    #pragma unroll
    for (int p = 0; p < 4; ++p) {
        f4 v = *(const f4*)(src + (size_t)(k0 + p * 16 + rk) * N + n0 + cn4);
        #pragma unroll
        for (int j = 0; j < 4; ++j) t2[cn4 + j][p * 16 + rk] = v[j];
    }
    __syncthreads();
    int n = tid >> 2, kb = (tid & 3) * 16;
    bh8 o0, o1;
    #pragma unroll
    for (int j = 0; j < 8; ++j) o0[j] = f2bf(t2[n][kb + j]);
    #pragma unroll
    for (int j = 0; j < 8; ++j) o1[j] = f2bf(t2[n][kb + 8 + j]);
    short* wp = d + (size_t)(n0 + n) * K + k0 + kb;
    *(bh8*)wp = o0;
    *(bh8*)(wp + 8) = o1;
}

// ---------------- embedding + LN0 ----------------
__global__ __launch_bounds__(256) void embed_ln0_k(
        const float* __restrict__ states, const float* __restrict__ actions,
        const float* __restrict__ goals, const int* __restrict__ timesteps,
        const float* __restrict__ W_s, const float* __restrict__ b_s,
        const float* __restrict__ W_a, const float* __restrict__ b_a,
        const float* __restrict__ W_g, const float* __restrict__ b_g,
        const float* __restrict__ E_t, const float* __restrict__ g0,
        const float* __restrict__ bb0, float* __restrict__ x, short* __restrict__ xb) {
    int row = blockIdx.x;
    int b = row / T3, t3 = row - b * T3;
    int t = t3 / 3, kind = t3 - t * 3;
    __shared__ float inv[64];
    __shared__ float xr[CDIM];
    __shared__ float red[4];
    int tid = threadIdx.x;
    const float* src; const float* W; const float* bias;
    if (kind == 0)      { src = goals + b * 64;                       W = W_g; bias = b_g; }
    else if (kind == 1) { src = states + ((size_t)b * SEQ + t) * 64;  W = W_s; bias = b_s; }
    else                { src = actions + ((size_t)b * SEQ + t) * 64; W = W_a; bias = b_a; }
    if (tid < 64) inv[tid] = src[tid];
    __syncthreads();
    int ts = timesteps[b * SEQ + t];
    for (int c = tid; c < CDIM; c += 256) {
        float acc = bias[c] + E_t[(size_t)ts * CDIM + c];
        #pragma unroll 8
        for (int kk = 0; kk < 64; ++kk) acc += inv[kk] * W[kk * CDIM + c];
        xr[c] = acc;
    }
    __syncthreads();
    float v0 = xr[tid], v1 = xr[tid + 256], v2 = xr[tid + 512];
    float mean = block_sum(v0 + v1 + v2, red, tid) * (1.f / CDIM);
    float d0 = v0 - mean, d1 = v1 - mean, d2 = v2 - mean;
    float var = block_sum(d0 * d0 + d1 * d1 + d2 * d2, red, tid) * (1.f / CDIM);
    float rs = rsqrtf(var + 1e-5f);
    float* w = x + (size_t)row * CDIM;
    short* wb = xb + (size_t)row * CDIM;
    float o0 = d0 * rs * g0[tid]       + bb0[tid];
    float o1 = d1 * rs * g0[tid + 256] + bb0[tid + 256];
    float o2 = d2 * rs * g0[tid + 512] + bb0[tid + 512];
    w[tid] = o0; w[tid + 256] = o1; w[tid + 512] = o2;
    wb[tid] = f2bf(o0); wb[tid + 256] = f2bf(o1); wb[tid + 512] = f2bf(o2);
}

// ---------------- LayerNorm (f32 in -> f32 + bf16 out) ----------------
__global__ __launch_bounds__(256) void ln_k(const float* __restrict__ in, float* __restrict__ outp,
                                            short* __restrict__ outb,
                                            const float* __restrict__ g, const float* __restrict__ bb) {
    int row = blockIdx.x, tid = threadIdx.x;
    __shared__ float red[4];
    const float* r = in + (size_t)row * CDIM;
    float v0 = r[tid], v1 = r[tid + 256], v2 = r[tid + 512];
    float mean = block_sum(v0 + v1 + v2, red, tid) * (1.f / CDIM);
    float d0 = v0 - mean, d1 = v1 - mean, d2 = v2 - mean;
    float var = block_sum(d0 * d0 + d1 * d1 + d2 * d2, red, tid) * (1.f / CDIM);
    float rs = rsqrtf(var + 1e-5f);
    float* w = outp + (size_t)row * CDIM;
    short* wb = outb + (size_t)row * CDIM;
    float o0 = d0 * rs * g[tid]       + bb[tid];
    float o1 = d1 * rs * g[tid + 256] + bb[tid + 256];
    float o2 = d2 * rs * g[tid + 512] + bb[tid + 512];
    w[tid] = o0; w[tid + 256] = o1; w[tid + 512] = o2;
    wb[tid] = f2bf(o0); wb[tid + 256] = f2bf(o1); wb[tid + 512] = f2bf(o2);
}

// ---------------- BMx128 MFMA GEMM, BK=64, swizzled LDS, gload staging ------
// A [M][K] bf16, B [N][K] bf16. EPI 0: QKV scatter (z: 0=Q,1=K,2=V^T)
// EPI 1: outF = acc + bias + res (f32);  EPI 2: outQ = bf16(gelu(acc+bias))
template<int BM, int EPI>
__global__ __launch_bounds__(256) void gemm3_k(
        const short* __restrict__ A, const short* __restrict__ B0,
        const short* __restrict__ B1, const short* __restrict__ B2,
        const float* __restrict__ bias0, const float* __restrict__ bias1,
        const float* __restrict__ bias2, const float* __restrict__ res,
        float* __restrict__ outF, short* __restrict__ outQ,
        short* __restrict__ outK, short* __restrict__ outV,
        int N, int K) {
    const short* Bw = B0; const float* bias = bias0; short* outB = outQ;
    int zid = 0;
    if (EPI == 0) {
        zid = blockIdx.z;
        if (zid == 1) { Bw = B1; bias = bias1; outB = outK; }
        else if (zid == 2) { Bw = B2; bias = bias2; outB = outV; }
    }
    __shared__ short As[BM * 64];
    __shared__ short Bs[128 * 64];
    int tid = threadIdx.x, lane = tid & 63, wave = tid >> 6;
    int wm = wave >> 1, wn = wave & 1, lr = lane & 15, lg = lane >> 4;
    int bm = blockIdx.y * BM, bn = blockIdx.x * 128;
    int rl = lane >> 3, ch = (lane & 7) ^ rl;
    constexpr int MI = BM / 32;
    f4 acc[MI][4] = {};
    for (int k0 = 0; k0 < K; k0 += 64) {
        #pragma unroll
        for (int j = 0; j < BM / 32; ++j)
            gload16(A + (size_t)(bm + wave * (BM / 4) + j * 8 + rl) * K + k0 + ch * 8,
                    As + (wave * (BM / 4) + j * 8) * 64);
        #pragma unroll
        for (int j = 0; j < 4; ++j)
            gload16(Bw + (size_t)(bn + wave * 32 + j * 8 + rl) * K + k0 + ch * 8,
                    Bs + (wave * 32 + j * 8) * 64);
        __syncthreads();
        bh8 af[MI][2], bf[4][2];
        #pragma unroll
        for (int mi = 0; mi < MI; ++mi)
        #pragma unroll
        for (int kk = 0; kk < 2; ++kk) {
            int m = wm * (BM / 2) + mi * 16 + lr;
            af[mi][kk] = *(const bh8*)(As + m * 64 + (((kk * 4 + lg) ^ (lr & 7)) * 8));
        }
        #pragma unroll
        for (int ni = 0; ni < 4; ++ni)
        #pragma unroll
        for (int kk = 0; kk < 2; ++kk) {
            int n = wn * 64 + ni * 16 + lr;
            bf[ni][kk] = *(const bh8*)(Bs + n * 64 + (((kk * 4 + lg) ^ (lr & 7)) * 8));
        }
        #pragma unroll
        for (int kk = 0; kk < 2; ++kk)
        #pragma unroll
        for (int mi = 0; mi < MI; ++mi)
        #pragma unroll
        for (int ni = 0; ni < 4; ++ni)
            acc[mi][ni] = __builtin_amdgcn_mfma_f32_16x16x32_bf16(af[mi][kk], bf[ni][kk], acc[mi][ni], 0, 0, 0);
        __syncthreads();
    }
    #pragma unroll
    for (int mi = 0; mi < MI; ++mi)
    #pragma unroll
    for (int ni = 0; ni < 4; ++ni)
    #pragma unroll
    for (int i = 0; i < 4; ++i) {
        int row = bm + wm * (BM / 2) + mi * 16 + lg * 4 + i;
        int col = bn + wn * 64 + ni * 16 + lr;
        float vv = acc[mi][ni][i] + bias[col];
        if (EPI == 0) {
            int b = row / T3, t = row - b * T3;
            int h = col >> 6, d = col & 63;
            if (zid == 2) outB[((size_t)(b * NH + h) * 64 + d) * T3 + t] = f2bf(vv);
            else          outB[((((size_t)b * NH + h) * T3 + t) << 6) + d] = f2bf(vv);
        } else if (EPI == 1) {
            outF[(size_t)row * N + col] = vv + res[(size_t)row * N + col];
        } else {
            float gl = 0.5f * vv * (1.0f + erff(vv * 0.70710678118f));
            outQ[(size_t)row * N + col] = f2bf(gl);
        }
    }
}

// ---------------- causal flash attention (no-max softmax, dbuf gload) -------
// q,k: [bh][T3][64] bf16 ; vt: [bh][64][T3] bf16 (pre-transposed by QKV gemm)
__global__ __launch_bounds__(256) void attn_k(const short* __restrict__ q, const short* __restrict__ k,
                                              const short* __restrict__ vt, short* __restrict__ att) {
    int idx = blockIdx.x;
    int qt = 23 - (idx / 24);          // heavy-first ordering
    int bh = idx % 24;
    int b = bh / NH, h = bh - b * NH;
    const short* qb = q  + (size_t)bh * T3 * HD;
    const short* kb = k  + (size_t)bh * T3 * HD;
    const short* vb = vt + (size_t)bh * HD * T3;
    __shared__ short Ks[2][4096];
    __shared__ short Vs[2][4096];
    __shared__ short Pl[4][16][72];
    int tid = threadIdx.x, lane = tid & 63, wave = tid >> 6;
    int lr = lane & 15, lg = lane >> 4;
    int rl = lane >> 3, ch = (lane & 7) ^ rl;
    int qrow0 = qt * 64 + wave * 16;
    bh8 aq0 = *(const bh8*)(qb + (size_t)(qrow0 + lr) * HD + lg * 8);
    bh8 aq1 = *(const bh8*)(qb + (size_t)(qrow0 + lr) * HD + 32 + lg * 8);
    f4 o[4] = {};
    float lsum[4] = {0.f, 0.f, 0.f, 0.f};

    auto STAGE = [&](int kt2, int buf) {
        const short* kb2 = kb + (size_t)kt2 * 64 * HD;
        #pragma unroll
        for (int j = 0; j < 2; ++j)
            gload16(kb2 + (wave * 16 + j * 8 + rl) * HD + ch * 8,
                    &Ks[buf][(wave * 16 + j * 8) * 64]);
        const short* vb2 = vb + kt2 * 64;
        #pragma unroll
        for (int j = 0; j < 2; ++j)
            gload16(vb2 + (size_t)(wave * 16 + j * 8 + rl) * T3 + ch * 8,
                    &Vs[buf][(wave * 16 + j * 8) * 64]);
    };

    STAGE(0, 0);
    int cur = 0;
    for (int kt = 0; kt <= qt; ++kt) {
        if (kt < qt) {
            STAGE(kt + 1, cur ^ 1);
            asm volatile("s_waitcnt vmcnt(4)" ::: "memory");
        } else {
            asm volatile("s_waitcnt vmcnt(0)" ::: "memory");
        }
        __builtin_amdgcn_s_barrier();
        __builtin_amdgcn_sched_barrier(0);
        const short* Kb = &Ks[cur][0];
        const short* Vb = &Vs[cur][0];
        f4 s[4];
        #pragma unroll
        for (int nf = 0; nf < 4; ++nf) {
            int tok = nf * 16 + lr;
            bh8 bk0 = *(const bh8*)(Kb + tok * 64 + ((lg ^ (lr & 7)) * 8));
            bh8 bk1 = *(const bh8*)(Kb + tok * 64 + (((4 + lg) ^ (lr & 7)) * 8));
            f4 t = {};
            t = __builtin_amdgcn_mfma_f32_16x16x32_bf16(aq0, bk0, t, 0, 0, 0);
            t = __builtin_amdgcn_mfma_f32_16x16x32_bf16(aq1, bk1, t, 0, 0, 0);
            s[nf] = t;
        }
        #pragma unroll
        for (int nf = 0; nf < 4; ++nf)
        #pragma unroll
        for (int i = 0; i < 4; ++i) {
            float p = __expf(s[nf][i] * 0.125f);
            if (kt == qt && (nf * 16 + lr) > (wave * 16 + lg * 4 + i)) p = 0.f;
            lsum[i] += p;
            Pl[wave][lg * 4 + i][nf * 16 + lr] = f2bf(p);
        }
        bh8 ap0 = *(const bh8*)&Pl[wave][lr][lg * 8];
        bh8 ap1 = *(const bh8*)&Pl[wave][lr][32 + lg * 8];
        #pragma unroll
        for (int nf = 0; nf < 4; ++nf) {
            int d = nf * 16 + lr;
            bh8 bv0 = *(const bh8*)(Vb + d * 64 + ((lg ^ (lr & 7)) * 8));
            bh8 bv1 = *(const bh8*)(Vb + d * 64 + (((4 + lg) ^ (lr & 7)) * 8));
            o[nf] = __builtin_amdgcn_mfma_f32_16x16x32_bf16(ap0, bv0, o[nf], 0, 0, 0);
            o[nf] = __builtin_amdgcn_mfma_f32_16x16x32_bf16(ap1, bv1, o[nf], 0, 0, 0);
        }
        __builtin_amdgcn_sched_barrier(0);
        __builtin_amdgcn_s_barrier();
        cur ^= 1;
    }
    float linv[4];
    #pragma unroll
    for (int i = 0; i < 4; ++i) {
        float l = lsum[i];
        #pragma unroll
        for (int off = 1; off < 16; off <<= 1) l += __shfl_xor(l, off, 16);
        linv[i] = 1.f / l;
    }
    #pragma unroll
    for (int nf = 0; nf < 4; ++nf)
    #pragma unroll
    for (int i = 0; i < 4; ++i) {
        int qrow = qrow0 + lg * 4 + i;
        att[((size_t)b * T3 + qrow) * CDIM + h * 64 + nf * 16 + lr] = f2bf(o[nf][i] * linv[i]);
    }
}

// ---------------- output heads ----------------
__global__ __launch_bounds__(64) void head_k(const float* __restrict__ x,
                                             const float* __restrict__ Wps, const float* __restrict__ bps,
                                             const float* __restrict__ Wpa, const float* __restrict__ bpa,
                                             float* __restrict__ out) {
    int o = blockIdx.y;
    int bs = blockIdx.x;
    int b = bs >> 9, t = bs & 511;
    int kind = (o == 0) ? 2 : 1;
    const float* W = (o == 0) ? Wps : Wpa;
    const float* bi = (o == 0) ? bps : bpa;
    const float* xr = x + ((size_t)b * T3 + t * 3 + kind) * CDIM;
    int n = threadIdx.x;
    float a0 = 0.f, a1 = 0.f, a2 = 0.f, a3 = 0.f;
    for (int kk = 0; kk < CDIM; kk += 4) {
        a0 = fmaf(xr[kk],     W[(kk)     * 64 + n], a0);
        a1 = fmaf(xr[kk + 1], W[(kk + 1) * 64 + n], a1);
        a2 = fmaf(xr[kk + 2], W[(kk + 2) * 64 + n], a2);
        a3 = fmaf(xr[kk + 3], W[(kk + 3) * 64 + n], a3);
    }
    float acc = bi[n] + ((a0 + a1) + (a2 + a3));
    if (o == 1) acc = tanhf(acc);
    out[(((size_t)o * 2 + b) * SEQ + t) * 64 + n] = acc;
}

extern "C" void kernel_launch(void* const* d_in, const int* in_sizes, int n_in,
                              void* d_out, int out_size, void* d_ws, size_t ws_size,
                              hipStream_t stream) {
    const float* states    = (const float*)d_in[0];
    const float* actions   = (const float*)d_in[1];
    const float* goals     = (const float*)d_in[2];
    const int*   timesteps = (const int*)d_in[4];
    const float* W_s = (const float*)d_in[5];  const float* b_s = (const float*)d_in[6];
    const float* W_a = (const float*)d_in[7];  const float* b_a = (const float*)d_in[8];
    const float* W_g = (const float*)d_in[9];  const float* b_g = (const float*)d_in[10];
    const float* E_t = (const float*)d_in[11];
    const float* ln0_g = (const float*)d_in[12]; const float* ln0_b = (const float*)d_in[13];
    const float* Wq = (const float*)d_in[14]; const float* bq = (const float*)d_in[15];
    const float* Wk = (const float*)d_in[16]; const float* bk = (const float*)d_in[17];
    const float* Wv = (const float*)d_in[18]; const float* bv = (const float*)d_in[19];
    const float* Wp = (const float*)d_in[20]; const float* bp = (const float*)d_in[21];
    const float* ln1_g = (const float*)d_in[22]; const float* ln1_b = (const float*)d_in[23];
    const float* W1 = (const float*)d_in[24]; const float* b1 = (const float*)d_in[25];
    const float* W2 = (const float*)d_in[26]; const float* b2 = (const float*)d_in[27];
    const float* ln2_g = (const float*)d_in[28]; const float* ln2_b = (const float*)d_in[29];
    const float* W_ps = (const float*)d_in[30]; const float* b_ps = (const float*)d_in[31];
    const float* W_pa = (const float*)d_in[32]; const float* b_pa = (const float*)d_in[33];

    char* ws = (char*)d_ws;
    float* x_f   = (float*)(ws);                    //  9.44 MB [3072][768] f32 residual
    float* x2_f  = (float*)(ws + 9437184);          //  9.44 MB
    short* x_bf  = (short*)(ws + 18874368);         //  4.72 MB [3072][768] bf16
    short* attb  = (short*)(ws + 23592960);         //  4.72 MB
    short* h_bf  = (short*)(ws + 28311552);         // 18.87 MB [3072][3072] bf16
    short* qb    = (short*)(ws + 47185920);         //  4.72 MB [B,H,T3,D] bf16
    short* kb    = (short*)(ws + 51904512);         //  4.72 MB [B,H,T3,D]
    short* vbt   = (short*)(ws + 56623104);         //  4.72 MB [B,H,D,T3]
    short* wts   = (short*)(ws + 61341696);         // 14.16 MB per-layer weights

    embed_ln0_k<<<dim3(2 * T3), 256, 0, stream>>>(states, actions, goals, timesteps,
        W_s, b_s, W_a, b_a, W_g, b_g, E_t, ln0_g, ln0_b, x_f, x_bf);

    for (int l = 0; l < NL; ++l) {
        size_t bo = (size_t)l * CDIM, b1o = (size_t)l * 4 * CDIM;
        conv64_k<<<dim3(1728), 256, 0, stream>>>(Wq, Wk, Wv, Wp, W1, W2, wts, l);
        short* Wqt = wts;
        short* Wkt = wts + 589824;
        short* Wvt = wts + 1179648;
        short* Wpt = wts + 1769472;
        short* W1t = wts + 2359296;
        short* W2t = wts + 4718592;

        gemm3_k<128, 0><<<dim3(6, 24, 3), 256, 0, stream>>>(x_bf, Wqt, Wkt, Wvt,
            bq + bo, bk + bo, bv + bo, nullptr, nullptr, qb, kb, vbt, CDIM, CDIM);
        attn_k<<<dim3(576), 256, 0, stream>>>(qb, kb, vbt, attb);
        gemm3_k<64, 1><<<dim3(6, 48, 1), 256, 0, stream>>>(attb, Wpt, nullptr, nullptr,
            bp + bo, nullptr, nullptr, x_f, x2_f, nullptr, nullptr, nullptr, CDIM, CDIM);
        ln_k<<<dim3(2 * T3), 256, 0, stream>>>(x2_f, x_f, x_bf, ln1_g + bo, ln1_b + bo);
        gemm3_k<128, 2><<<dim3(24, 24, 1), 256, 0, stream>>>(x_bf, W1t, nullptr, nullptr,
            b1 + b1o, nullptr, nullptr, nullptr, nullptr, h_bf, nullptr, nullptr, 4 * CDIM, CDIM);
        gemm3_k<64, 1><<<dim3(6, 48, 1), 256, 0, stream>>>(h_bf, W2t, nullptr, nullptr,
            b2 + bo, nullptr, nullptr, x_f, x2_f, nullptr, nullptr, nullptr, CDIM, 4 * CDIM);
        ln_k<<<dim3(2 * T3), 256, 0, stream>>>(x2_f, x_f, x_bf, ln2_g + bo, ln2_b + bo);
    }

    head_k<<<dim3(1024, 2), 64, 0, stream>>>(x_f, W_ps, b_ps, W_pa, b_pa, (float*)d_out);
}